// Round 4
// baseline (360.118 us; speedup 1.0000x reference)
//
#include <hip/hip_runtime.h>
#include <math.h>

// FullyConnectedTree: eval-mode layers are purely affine =>
//   out = x @ (W0@W1@W2) + (a0@W1@W2 + a1@W2 + a2) = x@v + c
// Kernel 1 folds the 64x64x64x1 weight chain into v[64], c (-> d_ws).
// Kernel 2 is a memory-bound B x 64 matvec (256 MB read, 4 MB write).

using vf4 = __attribute__((ext_vector_type(4))) float;  // native vec for nontemporal builtins

__device__ __forceinline__ float sigm(float x) { return 1.0f / (1.0f + expf(-x)); }

// 256 threads: 4 threads per output node (quad-shuffle reduce), float4 weight
// loads. Bounds the fold to a few microseconds independent of unrolling.
__global__ __launch_bounds__(256) void fold_weights(
        const float* __restrict__ el0, const float* __restrict__ el1,
        const float* __restrict__ el2, const float* __restrict__ es0,
        const float* __restrict__ es1, const float* __restrict__ es2,
        const float* __restrict__ b0, const float* __restrict__ b1,
        const float* __restrict__ b2, float* __restrict__ vc) {
    __shared__ float w2s[64];
    __shared__ float us[64];
    const int t = threadIdx.x;            // 0..255
    const float invT = 1.0f / 3.0f;

    if (t < 64) w2s[t] = sigm(el2[t] * invT) * es2[t];
    __syncthreads();

    const int j = t >> 2;                 // output node 0..63
    const int q = t & 3;                  // quad slice 0..3 (k = q*16..q*16+15)

    // u = W1 @ w2, W1[j][k] = sigmoid(el1[j][k]/T)*es1[j][k]
    {
        const float4* l4 = reinterpret_cast<const float4*>(el1 + j * 64 + q * 16);
        const float4* s4 = reinterpret_cast<const float4*>(es1 + j * 64 + q * 16);
        const float4* w4 = reinterpret_cast<const float4*>(&w2s[q * 16]);
        float p = 0.0f;
        #pragma unroll
        for (int i = 0; i < 4; ++i) {
            float4 l = l4[i], s = s4[i], w = w4[i];
            p += sigm(l.x * invT) * s.x * w.x + sigm(l.y * invT) * s.y * w.y
               + sigm(l.z * invT) * s.z * w.z + sigm(l.w * invT) * s.w * w.w;
        }
        p += __shfl_xor(p, 1);
        p += __shfl_xor(p, 2);
        if (q == 0) us[j] = p;
    }
    __syncthreads();

    // v = W0 @ u
    {
        const float4* l4 = reinterpret_cast<const float4*>(el0 + j * 64 + q * 16);
        const float4* s4 = reinterpret_cast<const float4*>(es0 + j * 64 + q * 16);
        const float4* u4 = reinterpret_cast<const float4*>(&us[q * 16]);
        float p = 0.0f;
        #pragma unroll
        for (int i = 0; i < 4; ++i) {
            float4 l = l4[i], s = s4[i], u = u4[i];
            p += sigm(l.x * invT) * s.x * u.x + sigm(l.y * invT) * s.y * u.y
               + sigm(l.z * invT) * s.z * u.z + sigm(l.w * invT) * s.w * u.w;
        }
        p += __shfl_xor(p, 1);
        p += __shfl_xor(p, 2);
        if (q == 0) vc[j] = p;
    }

    // c = sum_j a0[j]*u[j] + sum_j a1[j]*w2[j] + a2   (wave 0 only)
    if (t < 64) {
        float a0 = sigm(b0[t]) * 3.0f - 1.0f;
        float a1 = sigm(b1[t]) * 3.0f - 1.0f;
        float cp = a0 * us[t] + a1 * w2s[t];
        #pragma unroll
        for (int m = 1; m < 64; m <<= 1) cp += __shfl_xor(cp, m, 64);
        if (t == 0) vc[64] = cp + (sigm(b2[0]) * 3.0f - 1.0f);
    }
}

// 16 lanes per row, one float4 per lane: each wave loads 1024 contiguous bytes
// (4 full rows) per load instruction. Nontemporal loads (x streamed once).
// 4-way independent unroll: 4 outstanding 16B loads/thread -> 256 KB in
// flight per CU at full residency (2048 blocks = 8 blocks/CU = 32 waves/CU).
__global__ __launch_bounds__(256) void matvec64(
        const vf4* __restrict__ x4, const float* __restrict__ vc,
        float* __restrict__ out, int B) {
    const int lane16 = threadIdx.x & 15;
    const float4 vv = reinterpret_cast<const float4*>(vc)[lane16];
    const float c = vc[64];

    const int tid = blockIdx.x * blockDim.x + threadIdx.x;
    const int nthreads = gridDim.x * blockDim.x;
    const int grp = tid >> 4;         // row handled this iteration
    const int ngrp = nthreads >> 4;

    int row = grp;
    // main: 4 rows per thread per iteration (exact for B % (4*ngrp) == 0)
    for (; row + 3 * ngrp < B; row += 4 * ngrp) {
        const int r1 = row + ngrp, r2 = row + 2 * ngrp, r3 = row + 3 * ngrp;
        vf4 x0 = __builtin_nontemporal_load(&x4[row * 16 + lane16]);
        vf4 x1 = __builtin_nontemporal_load(&x4[r1  * 16 + lane16]);
        vf4 x2 = __builtin_nontemporal_load(&x4[r2  * 16 + lane16]);
        vf4 x3 = __builtin_nontemporal_load(&x4[r3  * 16 + lane16]);
        float s0 = x0.x * vv.x + x0.y * vv.y + x0.z * vv.z + x0.w * vv.w;
        float s1 = x1.x * vv.x + x1.y * vv.y + x1.z * vv.z + x1.w * vv.w;
        float s2 = x2.x * vv.x + x2.y * vv.y + x2.z * vv.z + x2.w * vv.w;
        float s3 = x3.x * vv.x + x3.y * vv.y + x3.z * vv.z + x3.w * vv.w;
        s0 += __shfl_xor(s0, 1); s1 += __shfl_xor(s1, 1);
        s2 += __shfl_xor(s2, 1); s3 += __shfl_xor(s3, 1);
        s0 += __shfl_xor(s0, 2); s1 += __shfl_xor(s1, 2);
        s2 += __shfl_xor(s2, 2); s3 += __shfl_xor(s3, 2);
        s0 += __shfl_xor(s0, 4); s1 += __shfl_xor(s1, 4);
        s2 += __shfl_xor(s2, 4); s3 += __shfl_xor(s3, 4);
        s0 += __shfl_xor(s0, 8); s1 += __shfl_xor(s1, 8);
        s2 += __shfl_xor(s2, 8); s3 += __shfl_xor(s3, 8);
        if (lane16 == 0) {
            __builtin_nontemporal_store(s0 + c, &out[row]);
            __builtin_nontemporal_store(s1 + c, &out[r1]);
            __builtin_nontemporal_store(s2 + c, &out[r2]);
            __builtin_nontemporal_store(s3 + c, &out[r3]);
        }
    }
    // tail (not taken for B = 1048576)
    for (; row < B; row += ngrp) {
        vf4 xv = __builtin_nontemporal_load(&x4[row * 16 + lane16]);
        float s = xv.x * vv.x + xv.y * vv.y + xv.z * vv.z + xv.w * vv.w;
        s += __shfl_xor(s, 1);
        s += __shfl_xor(s, 2);
        s += __shfl_xor(s, 4);
        s += __shfl_xor(s, 8);
        if (lane16 == 0) __builtin_nontemporal_store(s + c, &out[row]);
    }
}

extern "C" void kernel_launch(void* const* d_in, const int* in_sizes, int n_in,
                              void* d_out, int out_size, void* d_ws, size_t ws_size,
                              hipStream_t stream) {
    const float* x   = (const float*)d_in[0];
    const float* el0 = (const float*)d_in[1];
    const float* el1 = (const float*)d_in[2];
    const float* el2 = (const float*)d_in[3];
    const float* es0 = (const float*)d_in[4];
    const float* es1 = (const float*)d_in[5];
    const float* es2 = (const float*)d_in[6];
    const float* b0  = (const float*)d_in[7];
    const float* b1  = (const float*)d_in[8];
    const float* b2  = (const float*)d_in[9];
    float* out = (float*)d_out;
    float* vc  = (float*)d_ws;        // 65 floats: v[64] + c

    const int B = in_sizes[0] / 64;   // 1048576

    fold_weights<<<1, 256, 0, stream>>>(el0, el1, el2, es0, es1, es2, b0, b1, b2, vc);

    // 2048 blocks = 8 blocks/CU = full 32-wave residency in one dispatch batch;
    // each thread handles 32 rows (8 iterations of the 4-unrolled loop).
    matvec64<<<2048, 256, 0, stream>>>((const vf4*)x, vc, out, B);
}